// Round 1
// baseline (717.014 us; speedup 1.0000x reference)
//
#include <hip/hip_runtime.h>

// out[dst[e]*32 + c] += x[src[e]*32 + c]  for e in [0,E), c in [0,32)
// One thread per (edge, float4-chunk): E*8 threads, 16B vector gather,
// 4 hardware fp32 atomics (global_atomic_add_f32 via unsafeAtomicAdd).

#define D_FEAT 32

__global__ void __launch_bounds__(256)
mp_zero_kernel(float* __restrict__ out, int n) {
    int i = blockIdx.x * blockDim.x + threadIdx.x;
    if (i < n) out[i] = 0.0f;
}

__global__ void __launch_bounds__(256)
mp_scatter_kernel(const float* __restrict__ x,
                  const int* __restrict__ src,
                  const int* __restrict__ dst,
                  float* __restrict__ out,
                  int n_edges) {
    int idx = blockIdx.x * blockDim.x + threadIdx.x;
    int total = n_edges * 8;               // 8 float4 chunks per edge (D=32)
    if (idx >= total) return;
    int e = idx >> 3;
    int c = idx & 7;

    int s = src[e];
    int d = dst[e];

    const float4 v = *reinterpret_cast<const float4*>(x + (size_t)s * D_FEAT + c * 4);
    float* o = out + (size_t)d * D_FEAT + c * 4;

    // Hardware fp32 atomic add (no CAS loop). Denorm-flush semantics are
    // irrelevant for N(0,1) data; rounding is IEEE for the add itself.
    unsafeAtomicAdd(o + 0, v.x);
    unsafeAtomicAdd(o + 1, v.y);
    unsafeAtomicAdd(o + 2, v.z);
    unsafeAtomicAdd(o + 3, v.w);
}

extern "C" void kernel_launch(void* const* d_in, const int* in_sizes, int n_in,
                              void* d_out, int out_size, void* d_ws, size_t ws_size,
                              hipStream_t stream) {
    const float* x = (const float*)d_in[0];
    // edge_index is (2, E) row-major; JAX default config downcasts int64->int32.
    const int* edge_index = (const int*)d_in[1];
    int n_edges = in_sizes[1] / 2;
    const int* src = edge_index;            // row 0: source j
    const int* dst = edge_index + n_edges;  // row 1: target i

    float* out = (float*)d_out;

    // d_out is poisoned with 0xAA before every timed launch — zero it first.
    int zb = (out_size + 255) / 256;
    mp_zero_kernel<<<zb, 256, 0, stream>>>(out, out_size);

    int total = n_edges * 8;
    int gb = (total + 255) / 256;
    mp_scatter_kernel<<<gb, 256, 0, stream>>>(x, src, dst, out, n_edges);
}

// Round 2
// 302.095 us; speedup vs baseline: 2.3735x; 2.3735x over previous
//
#include <hip/hip_runtime.h>

// out[d] = sum_{e: dst[e]==d} x[src[e]]   (N=100k nodes, E=1.6M edges, D=32 f32)
//
// Round-1 lesson: fp32 global atomics write through to HBM at 16B granularity
// (51.2M atomics -> exactly 819.2 MB WRITE_SIZE). So: counting-sort by dst,
// then an atomic-free segmented reduction that writes each output once.

#define D_FEAT 32
typedef unsigned int u32;

// ---------------- phase kernels ----------------

__global__ void __launch_bounds__(256)
k_zero_u32(u32* __restrict__ p, int n) {
    int i = blockIdx.x * blockDim.x + threadIdx.x;
    if (i < n) p[i] = 0u;
}

__global__ void __launch_bounds__(256)
k_hist(const int* __restrict__ dst, u32* __restrict__ cnt, int n_edges) {
    int e = blockIdx.x * blockDim.x + threadIdx.x;
    if (e < n_edges) atomicAdd(&cnt[dst[e]], 1u);
}

// Block-level exclusive scan: 256 threads x 4 elems = 1024 elems/block.
__global__ void __launch_bounds__(256)
k_scan1(const u32* __restrict__ in, u32* __restrict__ out,
        u32* __restrict__ bsum, int n) {
    __shared__ u32 s[256];
    int t = threadIdx.x;
    int base = blockIdx.x * 1024 + t * 4;
    u32 v0 = (base + 0 < n) ? in[base + 0] : 0u;
    u32 v1 = (base + 1 < n) ? in[base + 1] : 0u;
    u32 v2 = (base + 2 < n) ? in[base + 2] : 0u;
    u32 v3 = (base + 3 < n) ? in[base + 3] : 0u;
    u32 sum = v0 + v1 + v2 + v3;
    s[t] = sum;
    __syncthreads();
    // Hillis-Steele inclusive scan over 256 thread sums
    for (int off = 1; off < 256; off <<= 1) {
        u32 x = (t >= off) ? s[t - off] : 0u;
        __syncthreads();
        if (t >= off) s[t] += x;
        __syncthreads();
    }
    if (t == 255) bsum[blockIdx.x] = s[255];
    u32 run = s[t] - sum;  // exclusive prefix for this thread
    if (base + 0 < n) out[base + 0] = run; run += v0;
    if (base + 1 < n) out[base + 1] = run; run += v1;
    if (base + 2 < n) out[base + 2] = run; run += v2;
    if (base + 3 < n) out[base + 3] = run;
}

// Single-block exclusive scan of block sums (nb <= 128).
__global__ void __launch_bounds__(128)
k_scan2(u32* __restrict__ bsum, int nb) {
    __shared__ u32 s[128];
    int t = threadIdx.x;
    u32 v = (t < nb) ? bsum[t] : 0u;
    s[t] = v;
    __syncthreads();
    for (int off = 1; off < 128; off <<= 1) {
        u32 x = (t >= off) ? s[t - off] : 0u;
        __syncthreads();
        if (t >= off) s[t] += x;
        __syncthreads();
    }
    if (t < nb) bsum[t] = s[t] - v;  // exclusive
}

// Add block offsets; also init cursor = offs and write offs[N] = E.
__global__ void __launch_bounds__(256)
k_scan3(u32* __restrict__ offs, u32* __restrict__ cur,
        const u32* __restrict__ bsum, int n, u32 total) {
    int i = blockIdx.x * blockDim.x + threadIdx.x;
    if (i < n) {
        u32 o = offs[i] + bsum[i >> 10];
        offs[i] = o;
        cur[i] = o;
    }
    if (i == 0) offs[n] = total;
}

__global__ void __launch_bounds__(256)
k_scatter(const int* __restrict__ src, const int* __restrict__ dst,
          u32* __restrict__ cur, u32* __restrict__ bin, int n_edges) {
    int e = blockIdx.x * blockDim.x + threadIdx.x;
    if (e >= n_edges) return;
    int d = dst[e];
    u32 pos = atomicAdd(&cur[d], 1u);
    bin[pos] = (u32)src[e];
}

// Thread per (node, float4-chunk): loop the node's bin segment, accumulate
// in registers, single coalesced 16B store. No atomics.
__global__ void __launch_bounds__(256)
k_gather(const float* __restrict__ x, const u32* __restrict__ offs,
         const u32* __restrict__ bin, float* __restrict__ out, int n_nodes) {
    int idx = blockIdx.x * blockDim.x + threadIdx.x;
    if (idx >= n_nodes * 8) return;
    int i = idx >> 3;
    int c = idx & 7;
    u32 beg = offs[i];
    u32 end = offs[i + 1];
    const float4* x4 = (const float4*)x;
    float4 acc = make_float4(0.f, 0.f, 0.f, 0.f);
    for (u32 k = beg; k < end; ++k) {
        u32 s = bin[k];
        float4 v = x4[(size_t)s * 8 + c];
        acc.x += v.x; acc.y += v.y; acc.z += v.z; acc.w += v.w;
    }
    ((float4*)out)[(size_t)i * 8 + c] = acc;
}

// ---------------- fallback (round-1 atomic path) ----------------

__global__ void __launch_bounds__(256)
mp_zero_kernel(float* __restrict__ out, int n) {
    int i = blockIdx.x * blockDim.x + threadIdx.x;
    if (i < n) out[i] = 0.0f;
}

__global__ void __launch_bounds__(256)
mp_scatter_kernel(const float* __restrict__ x, const int* __restrict__ src,
                  const int* __restrict__ dst, float* __restrict__ out,
                  int n_edges) {
    int idx = blockIdx.x * blockDim.x + threadIdx.x;
    if (idx >= n_edges * 8) return;
    int e = idx >> 3;
    int c = idx & 7;
    const float4 v = *reinterpret_cast<const float4*>(x + (size_t)src[e] * D_FEAT + c * 4);
    float* o = out + (size_t)dst[e] * D_FEAT + c * 4;
    unsafeAtomicAdd(o + 0, v.x);
    unsafeAtomicAdd(o + 1, v.y);
    unsafeAtomicAdd(o + 2, v.z);
    unsafeAtomicAdd(o + 3, v.w);
}

// ---------------- launch ----------------

extern "C" void kernel_launch(void* const* d_in, const int* in_sizes, int n_in,
                              void* d_out, int out_size, void* d_ws, size_t ws_size,
                              hipStream_t stream) {
    const float* x = (const float*)d_in[0];
    const int* edge_index = (const int*)d_in[1];
    int n_edges = in_sizes[1] / 2;
    const int* src = edge_index;            // row 0: source j
    const int* dst = edge_index + n_edges;  // row 1: target i
    float* out = (float*)d_out;
    int n_nodes = out_size / D_FEAT;

    // ws layout (u32): offs[N+1] | cur[N] | bsum[512] | bin[E]
    size_t need = ((size_t)(n_nodes + 1) + n_nodes + 512 + n_edges) * sizeof(u32);
    if (ws_size < need) {
        // fallback: atomic scatter (correct, slower)
        mp_zero_kernel<<<(out_size + 255) / 256, 256, 0, stream>>>(out, out_size);
        int total = n_edges * 8;
        mp_scatter_kernel<<<(total + 255) / 256, 256, 0, stream>>>(x, src, dst, out, n_edges);
        return;
    }

    u32* offs = (u32*)d_ws;
    u32* cur  = offs + (n_nodes + 1);
    u32* bsum = cur + n_nodes;
    u32* bin  = bsum + 512;

    int nb_scan = (n_nodes + 1023) / 1024;  // 98 for N=100k (fits k_scan2's 128)

    k_zero_u32<<<(n_nodes + 255) / 256, 256, 0, stream>>>(cur, n_nodes);
    k_hist<<<(n_edges + 255) / 256, 256, 0, stream>>>(dst, cur, n_edges);
    k_scan1<<<nb_scan, 256, 0, stream>>>(cur, offs, bsum, n_nodes);
    k_scan2<<<1, 128, 0, stream>>>(bsum, nb_scan);
    k_scan3<<<(n_nodes + 255) / 256, 256, 0, stream>>>(offs, cur, bsum, n_nodes, (u32)n_edges);
    k_scatter<<<(n_edges + 255) / 256, 256, 0, stream>>>(src, dst, cur, bin, n_edges);
    k_gather<<<(n_nodes * 8 + 255) / 256, 256, 0, stream>>>(x, offs, bin, out, n_nodes);
}